// Round 3
// baseline (207.766 us; speedup 1.0000x reference)
//
#include <hip/hip_runtime.h>
#include <math.h>

// 31x31 depthwise Gaussian (sigma=3) == separable 25-tap Gaussian applied
// twice (outer 3 taps of the 31 are exactly zero). Reflection effectively at
// radius 12 (reference pads 15 but the outer taps are zero).
//
// R6: R5 vertical-first structure, denser blocks.
//   - R5 (81.7us): occupancy 37.8% with NO resource cap (LDS fit 12 blocks,
//     VGPR 52) -> machine under-fed: 12288 short blocks + phase V only 75%
//     wave-filled (384 tasks = 1.5 rounds) + 96 staged cols vs 88 needed.
//   - R6: TH=64 -> 6144 blocks at 2x work each; stage exactly 88 cols
//     (MSTRIDE=89; phase-H read banks = (25r+8g+j)%32 -> exact 2-way, free);
//     phase V = 704 tasks (2 full rounds + 3-of-4-wave round), phase H = 512
//     tasks (exactly 2 full rounds). unroll 1 on outer loops keeps v[32]
//     single-allocated -> VGPR stays under the 64 occupancy cliff.
//     LDS 22784B -> 7 blocks/CU = 28 waves cap (87.5%).

#define IW 512
#define IH 512
#define RAD 12
#define TW 64                 // output tile width
#define TH 64                 // output tile height
#define MCOLS 88              // staged mid cols: exactly c0-12 .. c0+75
#define MSTRIDE 89            // 89%32==25; read pattern 2-way, write <=3-way
#define NTASKV (MCOLS * 8)    // 704 vertical tasks (8 output rows each)
#define NTASKH (TH * 8)       // 512 horizontal tasks

__global__ __launch_bounds__(256)
void gauss_blur_sep3_kernel(const float* __restrict__ x,
                            const float* __restrict__ wgt,
                            float* __restrict__ out)
{
    __shared__ float mid[TH * MSTRIDE];   // 5696 floats = 22784 B

    const int tid = threadIdx.x;
    const int z   = blockIdx.z;
    const int ch  = z % 3;

    // 1D kernel from 2D weight (uniform per block -> scalar loads):
    // k1[t] = w2d[15][3+t] / sqrt(w2d[15][15]), symmetric, t=0..12 held.
    float kk[13];
    {
        const float* __restrict__ wp = wgt + ch * 961 + 15 * 31;
        const float inv = 1.0f / sqrtf(wp[15]);
#pragma unroll
        for (int t = 0; t < 13; ++t) kk[t] = wp[3 + t] * inv;
    }

    const int r0g = blockIdx.y * TH;
    const int c0g = blockIdx.x * TW;
    const float* __restrict__ src = x + (size_t)z * (IW * IH);

    // ---------- phase V: vertical pass, global -> LDS mid -------------------
    // task (cp, rb): column c0g-12+cp (reflected), output rows r0g+8rb..+7,
    // input rows r0g+8rb-12 .. +19 (32 coalesced scalar loads, all in flight).
#pragma unroll 1
    for (int i = 0; i < 3; ++i) {
        const int task = tid + i * 256;
        if (i < 2 || task < NTASKV) {         // i==2: tid<192, wave-uniform
            const int rb = task / MCOLS;
            const int cp = task - rb * MCOLS;
            int gc = c0g - RAD + cp;
            gc = gc < 0 ? -gc : (gc >= IW ? 2 * IW - 2 - gc : gc);
            const int first = r0g + 8 * rb - RAD;

            float v[32];
            if (first >= 0 && first + 31 < IH) {
                const float* __restrict__ p = src + (size_t)first * IW + gc;
#pragma unroll
                for (int j = 0; j < 32; ++j) v[j] = p[(size_t)j * IW];
            } else {
#pragma unroll
                for (int j = 0; j < 32; ++j) {
                    int gr = first + j;
                    gr = gr < 0 ? -gr : (gr >= IH ? 2 * IH - 2 - gr : gr);
                    v[j] = src[(size_t)gr * IW + gc];
                }
            }
#pragma unroll
            for (int o = 0; o < 8; ++o) {
                float acc = v[o + 12] * kk[12];
#pragma unroll
                for (int t = 0; t < 12; ++t)
                    acc = fmaf(v[o + t] + v[o + 24 - t], kk[t], acc);
                mid[(8 * rb + o) * MSTRIDE + cp] = acc;
            }
        }
    }
    __syncthreads();

    // ---------- phase H: horizontal pass, LDS -> out ------------------------
    // task (r, g): row r, output cols c0g+8g .. +7; reads mid[r][8g+j],
    // bank = (25r + 8g + j)%32 -> exact 2-way (g vs g+4, 128B apart): free.
    // Stores: wave covers 8 rows x 256B contiguous per row.
    const int g  = tid & 7;
    const int r2 = tid >> 3;
#pragma unroll 1
    for (int i = 0; i < 2; ++i) {
        const int r = r2 + i * 32;
        const float* __restrict__ mrow = &mid[r * MSTRIDE + 8 * g];
        float v[32];
#pragma unroll
        for (int j = 0; j < 32; ++j) v[j] = mrow[j];

        float acc[8];
#pragma unroll
        for (int o = 0; o < 8; ++o) {
            float a = v[o + 12] * kk[12];
#pragma unroll
            for (int t = 0; t < 12; ++t)
                a = fmaf(v[o + t] + v[o + 24 - t], kk[t], a);
            acc[o] = a;
        }

        float* __restrict__ dst = out + (size_t)z * (IW * IH)
                                + (size_t)(r0g + r) * IW + c0g + 8 * g;
        *(float4*)(dst + 0) = make_float4(acc[0], acc[1], acc[2], acc[3]);
        *(float4*)(dst + 4) = make_float4(acc[4], acc[5], acc[6], acc[7]);
    }
}

extern "C" void kernel_launch(void* const* d_in, const int* in_sizes, int n_in,
                              void* d_out, int out_size, void* d_ws, size_t ws_size,
                              hipStream_t stream)
{
    const float* x   = (const float*)d_in[0];
    const float* wgt = (const float*)d_in[1];
    float* out = (float*)d_out;

    dim3 grid(IW / TW, IH / TH, 96);   // 8 x 8 x 96 = 6144 blocks
    gauss_blur_sep3_kernel<<<grid, dim3(256), 0, stream>>>(x, wgt, out);
}

// Round 4
// 204.163 us; speedup vs baseline: 1.0176x; 1.0176x over previous
//
#include <hip/hip_runtime.h>
#include <math.h>

// 31x31 depthwise Gaussian (sigma=3) == separable 25-tap Gaussian applied
// twice (outer 3 taps of the 31 are exactly zero). Reflection effectively at
// radius 12 (reference pads 15 but the outer taps are zero).
//
// R7: R5 vertical-first structure, wider tile in X.
//   - R5 (81.7us): TW=64, 1.375x vertical amplification, 12288 blocks,
//     VGPR 52, occupancy 38%, VALUBusy 57%.
//   - R6 (89us, reverted): TH=64 pushed VGPR to 72 -> over the 64-reg cliff,
//     waves/SIMD 8->4, occupancy 27%. Lesson: grow X, not Y (Y growth makes
//     longer per-task register chains; X growth adds tasks of the SAME shape).
//   - R7: TW=128 -> amplification 152/128=1.19 (-13.6% phase-V work), 6144
//     blocks, per-task shape unchanged so VGPR stays ~52. Phase H does two
//     column-halves per thread (g, g+8) to keep the wave footprint r0..7 x
//     g0..7 -> bank = (25r+8g+j)%32 covers all 32 banks x2 = conflict-free
//     (the naive 16-group mapping would be 4-way). LDS 19.6KB -> 8 blocks/CU.

#define IW 512
#define IH 512
#define RAD 12
#define TW 128                // output tile width
#define TH 32                 // output tile height
#define MCOLS 152             // staged mid cols: exactly c0-12 .. c0+139
#define MSTRIDE 153           // 153%32==25 -> verified conflict-free patterns
#define NTASKV (MCOLS * 4)    // 608 vertical tasks (8 output rows each)

__global__ __launch_bounds__(256)
void gauss_blur_sep3_kernel(const float* __restrict__ x,
                            const float* __restrict__ wgt,
                            float* __restrict__ out)
{
    __shared__ float mid[TH * MSTRIDE];   // 4896 floats = 19584 B

    const int tid = threadIdx.x;
    const int z   = blockIdx.z;
    const int ch  = z % 3;

    // 1D kernel from 2D weight (uniform per block -> scalar loads):
    // k1[t] = w2d[15][3+t] / sqrt(w2d[15][15]), symmetric, t=0..12 held.
    float kk[13];
    {
        const float* __restrict__ wp = wgt + ch * 961 + 15 * 31;
        const float inv = 1.0f / sqrtf(wp[15]);
#pragma unroll
        for (int t = 0; t < 13; ++t) kk[t] = wp[3 + t] * inv;
    }

    const int r0g = blockIdx.y * TH;
    const int c0g = blockIdx.x * TW;
    const float* __restrict__ src = x + (size_t)z * (IW * IH);

    // ---------- phase V: vertical pass, global -> LDS mid -------------------
    // task (cp, rb): column c0g-12+cp (reflected), output rows r0g+8rb..+7,
    // input rows r0g+8rb-12 .. +19 (32 coalesced scalar loads, all in flight).
#pragma unroll 1
    for (int i = 0; i < 3; ++i) {
        const int task = tid + i * 256;
        if (i < 2 || task < NTASKV) {         // i==2: tid<96
            const int rb = task / MCOLS;
            const int cp = task - rb * MCOLS;
            int gc = c0g - RAD + cp;
            gc = gc < 0 ? -gc : (gc >= IW ? 2 * IW - 2 - gc : gc);
            const int first = r0g + 8 * rb - RAD;

            float v[32];
            if (first >= 0 && first + 31 < IH) {
                const float* __restrict__ p = src + (size_t)first * IW + gc;
#pragma unroll
                for (int j = 0; j < 32; ++j) v[j] = p[(size_t)j * IW];
            } else {
#pragma unroll
                for (int j = 0; j < 32; ++j) {
                    int gr = first + j;
                    gr = gr < 0 ? -gr : (gr >= IH ? 2 * IH - 2 - gr : gr);
                    v[j] = src[(size_t)gr * IW + gc];
                }
            }
#pragma unroll
            for (int o = 0; o < 8; ++o) {
                float acc = v[o + 12] * kk[12];
#pragma unroll
                for (int t = 0; t < 12; ++t)
                    acc = fmaf(v[o + t] + v[o + 24 - t], kk[t], acc);
                // lanes = consecutive cp within a task row -> conflict-free
                mid[(8 * rb + o) * MSTRIDE + cp] = acc;
            }
        }
    }
    __syncthreads();

    // ---------- phase H: horizontal pass, LDS -> out ------------------------
    // thread (r = tid>>3, g = tid&7) handles two column-halves h=0,1:
    // output cols c0g + 8g + 64h + [0..7]; reads mid[r][8g+64h+j], j=0..31.
    // Wave footprint r0..7 x g0..7: bank = (25r+8g+j)%32 -> all 32 banks x2,
    // conflict-free. Stores: 8 rows x 2x16B per row per wave, coalesced.
    const int g = tid & 7;
    const int r = tid >> 3;
#pragma unroll 1
    for (int h = 0; h < 2; ++h) {
        const float* __restrict__ mrow = &mid[r * MSTRIDE + 8 * g + 64 * h];
        float v[32];
#pragma unroll
        for (int j = 0; j < 32; ++j) v[j] = mrow[j];

        float acc[8];
#pragma unroll
        for (int o = 0; o < 8; ++o) {
            float a = v[o + 12] * kk[12];
#pragma unroll
            for (int t = 0; t < 12; ++t)
                a = fmaf(v[o + t] + v[o + 24 - t], kk[t], a);
            acc[o] = a;
        }

        float* __restrict__ dst = out + (size_t)z * (IW * IH)
                                + (size_t)(r0g + r) * IW + c0g + 8 * g + 64 * h;
        *(float4*)(dst + 0) = make_float4(acc[0], acc[1], acc[2], acc[3]);
        *(float4*)(dst + 4) = make_float4(acc[4], acc[5], acc[6], acc[7]);
    }
}

extern "C" void kernel_launch(void* const* d_in, const int* in_sizes, int n_in,
                              void* d_out, int out_size, void* d_ws, size_t ws_size,
                              hipStream_t stream)
{
    const float* x   = (const float*)d_in[0];
    const float* wgt = (const float*)d_in[1];
    float* out = (float*)d_out;

    dim3 grid(IW / TW, IH / TH, 96);   // 4 x 16 x 96 = 6144 blocks
    gauss_blur_sep3_kernel<<<grid, dim3(256), 0, stream>>>(x, wgt, out);
}